// Round 1
// baseline (969.145 us; speedup 1.0000x reference)
//
#include <hip/hip_runtime.h>
#include <hip/hip_bf16.h>

#define ALPHA 0.01f

typedef __attribute__((ext_vector_type(8))) __bf16 bf16x8;
typedef __attribute__((ext_vector_type(4))) float f32x4;

#define BATCH 32
#define P1H 97
#define P1W 127
#define P2H 47
#define P2W 62
#define FLAT 186496
#define NCH 729
#define BKC 256

static __device__ __forceinline__ unsigned short f2bf(float x) {
  union { float f; unsigned u; } c; c.f = x;
  unsigned r = c.u + 0x7fffu + ((c.u >> 16) & 1u);
  return (unsigned short)(r >> 16);
}

// ---------------- conv1 (3x3x1->32) + ReLU + 2x2 maxpool, out bf16 ----------------
__global__ __launch_bounds__(256) void conv1_pool(const float* __restrict__ x,
    const float* __restrict__ w1, const float* __restrict__ b1,
    unsigned short* __restrict__ p1) {
  int pid = blockIdx.x * 256 + threadIdx.x;
  if (pid >= BATCH * P1H * P1W) return;
  int b = pid / (P1H * P1W);
  int rem = pid - b * (P1H * P1W);
  int ph = rem / P1W;
  int pw = rem - ph * P1W;
  const float* xb = x + ((b * 197 + 2 * ph) * 256 + 2 * pw);
  float in[4][4];
#pragma unroll
  for (int r = 0; r < 4; ++r) {
    float2 v0 = *reinterpret_cast<const float2*>(xb + r * 256);
    float2 v1 = *reinterpret_cast<const float2*>(xb + r * 256 + 2);
    in[r][0] = v0.x; in[r][1] = v0.y; in[r][2] = v1.x; in[r][3] = v1.y;
  }
  unsigned pk[16];
#pragma unroll
  for (int c = 0; c < 32; ++c) {
    float s00 = b1[c], s01 = s00, s10 = s00, s11 = s00;
#pragma unroll
    for (int ky = 0; ky < 3; ++ky)
#pragma unroll
      for (int kx = 0; kx < 3; ++kx) {
        float w = w1[(ky * 3 + kx) * 32 + c];
        s00 = fmaf(in[ky][kx], w, s00);
        s01 = fmaf(in[ky][kx + 1], w, s01);
        s10 = fmaf(in[ky + 1][kx], w, s10);
        s11 = fmaf(in[ky + 1][kx + 1], w, s11);
      }
    float m = fmaxf(fmaxf(s00, s01), fmaxf(s10, s11));
    m = fmaxf(m, 0.0f);
    unsigned short u = f2bf(m);
    if (c & 1) pk[c >> 1] |= ((unsigned)u) << 16;
    else pk[c >> 1] = (unsigned)u;
  }
  uint4* dst = reinterpret_cast<uint4*>(p1 + (size_t)pid * 32);
#pragma unroll
  for (int g = 0; g < 4; ++g)
    dst[g] = make_uint4(pk[g * 4], pk[g * 4 + 1], pk[g * 4 + 2], pk[g * 4 + 3]);
}

// ---------------- repack conv2 weights (3,3,32,64) f32 -> bf16 MFMA B-fragments ----
// layout: frag f = tap*4+nf ; element ((f*64+lane)*8+j) = w2[tap][k][n],
//         k = (lane>>4)*8+j , n = nf*16 + (lane&15)
__global__ __launch_bounds__(256) void repack_w2(const float* __restrict__ w2,
                                                 unsigned short* __restrict__ bpack) {
  int o = blockIdx.x * 256 + threadIdx.x;
  if (o >= 9 * 4 * 512) return;
  int f = o >> 9;
  int within = o & 511;
  int lane = within >> 3, j = within & 7;
  int tap = f >> 2, nf = f & 3;
  int k = ((lane >> 4) << 3) + j;
  int n = nf * 16 + (lane & 15);
  bpack[o] = f2bf(w2[(tap * 32 + k) * 64 + n]);
}

// ---------------- conv2 (3x3x32->64) MFMA + bias + ReLU + 2x2 maxpool -> h f32 -----
__global__ __launch_bounds__(256) void conv2_pool(const unsigned short* __restrict__ p1,
    const unsigned short* __restrict__ bpack, const float* __restrict__ b2,
    float* __restrict__ h) {
  __shared__ alignas(16) unsigned char lds_buf[65536];
  int prow = blockIdx.x, b = blockIdx.y;
  int tid = threadIdx.x;
  int lane = tid & 63, wid = tid >> 6;
  {
    const uint4* src = reinterpret_cast<const uint4*>(bpack);
    uint4* dst = reinterpret_cast<uint4*>(lds_buf);
    for (int i = tid; i < 2304; i += 256) dst[i] = src[i];
  }
  __syncthreads();
  int row = lane & 15, kg = lane >> 4;
  int rowbase[4];
  int coff[4][3];
#pragma unroll
  for (int mf = 0; mf < 4; ++mf) {
    int m = wid * 64 + mf * 16 + row;
    int cro = m >> 7, cc = m & 127;
    rowbase[mf] = ((b * 97 + 2 * prow + cro) * 127) * 32 + kg * 8;
#pragma unroll
    for (int kx = 0; kx < 3; ++kx) {
      int ic = cc + kx; if (ic > 126) ic = 126;
      coff[mf][kx] = ic * 32;
    }
  }
  f32x4 acc[4][4];
#pragma unroll
  for (int i = 0; i < 4; ++i)
#pragma unroll
    for (int j = 0; j < 4; ++j) acc[i][j] = (f32x4){0.f, 0.f, 0.f, 0.f};

  const bf16x8* bl = reinterpret_cast<const bf16x8*>(lds_buf);
#pragma unroll
  for (int ky = 0; ky < 3; ++ky) {
#pragma unroll
    for (int kx = 0; kx < 3; ++kx) {
      int tap = ky * 3 + kx;
      bf16x8 a[4];
#pragma unroll
      for (int mf = 0; mf < 4; ++mf) {
        int addr = rowbase[mf] + ky * (127 * 32) + coff[mf][kx];
        a[mf] = *reinterpret_cast<const bf16x8*>(p1 + addr);
      }
      bf16x8 bf[4];
#pragma unroll
      for (int nf = 0; nf < 4; ++nf) bf[nf] = bl[(tap * 4 + nf) * 64 + lane];
#pragma unroll
      for (int nf = 0; nf < 4; ++nf)
#pragma unroll
        for (int mf = 0; mf < 4; ++mf)
          acc[mf][nf] = __builtin_amdgcn_mfma_f32_16x16x32_bf16(a[mf], bf[nf], acc[mf][nf], 0, 0, 0);
    }
  }
  __syncthreads();
  float* stage = reinterpret_cast<float*>(lds_buf);
#pragma unroll
  for (int mf = 0; mf < 4; ++mf)
#pragma unroll
    for (int nf = 0; nf < 4; ++nf) {
      int ch = nf * 16 + (lane & 15);
      float bias = b2[ch];
#pragma unroll
      for (int j = 0; j < 4; ++j) {
        int m = wid * 64 + mf * 16 + (lane >> 4) * 4 + j;
        float v = acc[mf][nf][j] + bias;
        stage[m * 64 + ch] = fmaxf(v, 0.f);
      }
    }
  __syncthreads();
  float* hb = h + (size_t)b * FLAT + prow * (P2W * 64);
  for (int o = tid; o < P2W * 64; o += 256) {
    int pw = o >> 6, ch = o & 63;
    int c0 = 2 * pw;
    float v = fmaxf(fmaxf(stage[c0 * 64 + ch], stage[(c0 + 1) * 64 + ch]),
                    fmaxf(stage[(128 + c0) * 64 + ch], stage[(129 + c0) * 64 + ch]));
    hb[o] = v;
  }
}

// ---------------- transpose h (32 x FLAT) -> hT (FLAT x 32) ----------------
__global__ __launch_bounds__(256) void transpose_h(const float* __restrict__ h,
                                                   float* __restrict__ hT) {
  int f = blockIdx.x * 256 + threadIdx.x;
  if (f >= FLAT) return;
  float v[32];
#pragma unroll
  for (int m = 0; m < 32; ++m) v[m] = h[(size_t)m * FLAT + f];
  float4* dst = reinterpret_cast<float4*>(hT + (size_t)f * 32);
#pragma unroll
  for (int g = 0; g < 8; ++g)
    dst[g] = make_float4(v[4 * g], v[4 * g + 1], v[4 * g + 2], v[4 * g + 3]);
}

// ---------------- big skinny GEMM: partial[chunk][32][N] over K-chunks ----------
template <int N>
__global__ __launch_bounds__(N / 2) void gemm_big(const float* __restrict__ W,
    const float* __restrict__ hT, float* __restrict__ partial) {
  int tid = threadIdx.x;
  int k0 = blockIdx.x * BKC;
  int kend = k0 + BKC; if (kend > FLAT) kend = FLAT;
  const float2* Wv = reinterpret_cast<const float2*>(W);
  float2 acc[32];
#pragma unroll
  for (int m = 0; m < 32; ++m) acc[m] = make_float2(0.f, 0.f);
#pragma unroll 2
  for (int k = k0; k < kend; ++k) {
    float2 w = Wv[(size_t)k * (N / 2) + tid];
    const float* hr = hT + (size_t)k * 32;
#pragma unroll
    for (int m = 0; m < 32; ++m) {
      acc[m].x = fmaf(hr[m], w.x, acc[m].x);
      acc[m].y = fmaf(hr[m], w.y, acc[m].y);
    }
  }
  float2* out = reinterpret_cast<float2*>(partial + (size_t)blockIdx.x * 32 * N);
#pragma unroll
  for (int m = 0; m < 32; ++m) out[m * (N / 2) + tid] = acc[m];
}

// ---------------- reduce partials + bias + leaky -> y1 (32x512), z1 (32x256) ------
__global__ __launch_bounds__(256) void reduce_big(const float* __restrict__ part1,
    const float* __restrict__ part2, const float* __restrict__ b_c1,
    const float* __restrict__ b_r1, float* __restrict__ y1, float* __restrict__ z1) {
  int t = blockIdx.x * 256 + threadIdx.x;
  float s = 0.f;
  if (t < 32 * 512) {
    int m = t >> 9, n = t & 511;
    const float* p = part1 + m * 512 + n;
#pragma unroll 4
    for (int c = 0; c < NCH; ++c) s += p[(size_t)c * (32 * 512)];
    s += b_c1[n];
    y1[t] = s > 0.f ? s : ALPHA * s;
  } else {
    int u = t - 32 * 512;
    int m = u >> 8, n = u & 255;
    const float* p = part2 + m * 256 + n;
#pragma unroll 4
    for (int c = 0; c < NCH; ++c) s += p[(size_t)c * (32 * 256)];
    s += b_r1[n];
    z1[u] = s > 0.f ? s : ALPHA * s;
  }
}

// ---------------- small dense: out[m][n] = (leaky)(A[m]@W + bias) ----------------
template <bool LK>
__global__ void dense_k(const float* __restrict__ A, const float* __restrict__ W,
                        const float* __restrict__ bias, float* __restrict__ out,
                        int K, int N) {
  int n = blockIdx.x * blockDim.x + threadIdx.x;
  int m = blockIdx.y;
  if (n >= N) return;
  const float* a = A + (size_t)m * K;
  float s = bias[n];
  for (int k = 0; k < K; ++k) s = fmaf(a[k], W[(size_t)k * N + n], s);
  if (LK) s = s > 0.f ? s : ALPHA * s;
  out[(size_t)m * N + n] = s;
}

// ---------------- heads ----------------
__global__ __launch_bounds__(256) void class_head(const float* __restrict__ y3,
    const float* __restrict__ w_sm, const float* __restrict__ b_sm,
    float* __restrict__ out) {
  int r = blockIdx.x * 256 + threadIdx.x;
  if (r >= 32 * 225) return;
  const float* y = y3 + (size_t)r * 13;
  float v[13];
#pragma unroll
  for (int i = 0; i < 13; ++i) v[i] = y[i];
  float l[13];
  float mx = -1e30f;
#pragma unroll
  for (int j = 0; j < 13; ++j) {
    float s = b_sm[j];
#pragma unroll
    for (int i = 0; i < 13; ++i) s = fmaf(v[i], w_sm[i * 13 + j], s);
    l[j] = s; mx = fmaxf(mx, s);
  }
  float sum = 0.f;
#pragma unroll
  for (int j = 0; j < 13; ++j) { l[j] = expf(l[j] - mx); sum += l[j]; }
  float inv = 1.f / sum;
  float* o = out + (size_t)r * 13;
#pragma unroll
  for (int j = 0; j < 13; ++j) o[j] = l[j] * inv;
}

__global__ __launch_bounds__(256) void reg_head(const float* __restrict__ zo,
    const float* __restrict__ w_sg, const float* __restrict__ b_sg,
    float* __restrict__ out) {
  int r = blockIdx.x * 256 + threadIdx.x;
  if (r >= 32 * 225) return;
  const float* z = zo + (size_t)r * 4;
  float v[4];
#pragma unroll
  for (int i = 0; i < 4; ++i) v[i] = z[i];
  float* o = out + (size_t)r * 4;
#pragma unroll
  for (int j = 0; j < 4; ++j) {
    float s = b_sg[j];
#pragma unroll
    for (int i = 0; i < 4; ++i) s = fmaf(v[i], w_sg[i * 4 + j], s);
    o[j] = 1.f / (1.f + expf(-s));
  }
}

// ---------------- workspace layout (bytes) ----------------
#define OFF_P1     ((size_t)0)                    // 25,229,312  (dead after conv2)
#define OFF_PART1  ((size_t)0)                    // 47,775,744  (overlays p1)
#define OFF_BPACK  ((size_t)47775744)             // 36,864
#define OFF_H      ((size_t)47812608)             // 23,871,488  (dead after transpose)
#define OFF_PART2  ((size_t)47812608)             // 23,887,872  (overlays h)
#define OFF_HT     ((size_t)71700480)             // 23,871,488
#define OFF_Y1     ((size_t)95571968)
#define OFF_Y2     ((size_t)95637504)
#define OFF_Y3     ((size_t)95670272)
#define OFF_Z1     ((size_t)96044800)
#define OFF_Z2     ((size_t)96077568)
#define OFF_Z3     ((size_t)96093952)
#define OFF_Z4     ((size_t)96110336)
#define OFF_ZO     ((size_t)96118528)

extern "C" void kernel_launch(void* const* d_in, const int* in_sizes, int n_in,
                              void* d_out, int out_size, void* d_ws, size_t ws_size,
                              hipStream_t stream) {
  const float* x     = (const float*)d_in[0];
  const float* w1    = (const float*)d_in[1];
  const float* b1    = (const float*)d_in[2];
  const float* w2    = (const float*)d_in[3];
  const float* b2    = (const float*)d_in[4];
  const float* w_c1  = (const float*)d_in[5];
  const float* b_c1  = (const float*)d_in[6];
  const float* w_c2  = (const float*)d_in[7];
  const float* b_c2  = (const float*)d_in[8];
  const float* w_co  = (const float*)d_in[9];
  const float* b_co  = (const float*)d_in[10];
  const float* w_sm  = (const float*)d_in[11];
  const float* b_sm  = (const float*)d_in[12];
  const float* w_r1  = (const float*)d_in[13];
  const float* b_r1  = (const float*)d_in[14];
  const float* w_r2  = (const float*)d_in[15];
  const float* b_r2  = (const float*)d_in[16];
  const float* w_r3  = (const float*)d_in[17];
  const float* b_r3  = (const float*)d_in[18];
  const float* w_r4  = (const float*)d_in[19];
  const float* b_r4  = (const float*)d_in[20];
  const float* w_ro  = (const float*)d_in[21];
  const float* b_ro  = (const float*)d_in[22];
  const float* w_sg  = (const float*)d_in[23];
  const float* b_sg  = (const float*)d_in[24];

  char* ws = (char*)d_ws;
  unsigned short* p1    = (unsigned short*)(ws + OFF_P1);
  float*          part1 = (float*)(ws + OFF_PART1);
  unsigned short* bpack = (unsigned short*)(ws + OFF_BPACK);
  float*          h     = (float*)(ws + OFF_H);
  float*          part2 = (float*)(ws + OFF_PART2);
  float*          hT    = (float*)(ws + OFF_HT);
  float*          y1    = (float*)(ws + OFF_Y1);
  float*          y2    = (float*)(ws + OFF_Y2);
  float*          y3    = (float*)(ws + OFF_Y3);
  float*          z1    = (float*)(ws + OFF_Z1);
  float*          z2    = (float*)(ws + OFF_Z2);
  float*          z3    = (float*)(ws + OFF_Z3);
  float*          z4    = (float*)(ws + OFF_Z4);
  float*          zo    = (float*)(ws + OFF_ZO);

  float* class_out = (float*)d_out;
  float* reg_out   = (float*)d_out + 32 * 225 * 13;

  conv1_pool<<<1540, 256, 0, stream>>>(x, w1, b1, p1);
  repack_w2<<<72, 256, 0, stream>>>(w2, bpack);
  conv2_pool<<<dim3(47, 32), 256, 0, stream>>>(p1, bpack, b2, h);
  transpose_h<<<729, 256, 0, stream>>>(h, hT);
  gemm_big<512><<<729, 256, 0, stream>>>(w_c1, hT, part1);
  gemm_big<256><<<729, 128, 0, stream>>>(w_r1, hT, part2);
  reduce_big<<<96, 256, 0, stream>>>(part1, part2, b_c1, b_r1, y1, z1);
  dense_k<true><<<dim3(1, 32), 256, 0, stream>>>(y1, w_c2, b_c2, y2, 512, 256);
  dense_k<true><<<dim3(12, 32), 256, 0, stream>>>(y2, w_co, b_co, y3, 256, 2925);
  class_head<<<29, 256, 0, stream>>>(y3, w_sm, b_sm, class_out);
  dense_k<true><<<dim3(1, 32), 128, 0, stream>>>(z1, w_r2, b_r2, z2, 256, 128);
  dense_k<true><<<dim3(1, 32), 128, 0, stream>>>(z2, w_r3, b_r3, z3, 128, 128);
  dense_k<true><<<dim3(1, 32), 64, 0, stream>>>(z3, w_r4, b_r4, z4, 128, 64);
  dense_k<false><<<dim3(4, 32), 256, 0, stream>>>(z4, w_ro, b_ro, zo, 64, 900);
  reg_head<<<29, 256, 0, stream>>>(zo, w_sg, b_sg, reg_out);
}